// Round 19
// baseline (857.695 us; speedup 1.0000x reference)
//
#include <hip/hip_runtime.h>
#include <hip/hip_bf16.h>

typedef __attribute__((ext_vector_type(8))) short short8;
typedef __attribute__((ext_vector_type(4))) float f32x4;

#define T_TOK 8192
#define DMODEL 1024
#define HFFN 4096
#define NEXP 4

__device__ __forceinline__ ushort f2b(float f) {
    __hip_bfloat16 h = __float2bfloat16(f);
    return __builtin_bit_cast(ushort, h);
}
__device__ __forceinline__ float b2f(unsigned u) {  // low 16 bits = bf16
    return __builtin_bit_cast(float, u << 16);
}

__device__ __forceinline__ void glds16(const void* g, void* l) {
    __builtin_amdgcn_global_load_lds(
        (__attribute__((address_space(1))) void*)g,
        (__attribute__((address_space(3))) void*)l, 16, 0, 0);
}

__device__ __forceinline__ float gelu_f(float v) {
    float v2 = v * v;
    float t2 = __builtin_fmaf(0.044715f, v2 * v, v);
    float e = __builtin_amdgcn_exp2f(2.3022082f * t2);   // 1.5957691216*log2(e)
    float rr = __builtin_amdgcn_rcpf(e + 1.0f);
    return v - v * rr;
}

// ---------------- gate + x->bf16 fusion + ballot routing + inverse index -----
__global__ __launch_bounds__(256) void gate_kernel(
        const float* __restrict__ x, const float* __restrict__ gw,
        ushort* __restrict__ Xb, float* __restrict__ gdense,
        int* __restrict__ counts, int* __restrict__ lists,
        int* __restrict__ inv) {
    const int lane = threadIdx.x & 63;
    const int w = threadIdx.x >> 6;
    __shared__ int top2s[32];

    float4 wv[4][4];
#pragma unroll
    for (int p = 0; p < 4; p++)
#pragma unroll
        for (int e = 0; e < 4; e++)
            wv[p][e] = *(const float4*)&gw[e * DMODEL + p * 256 + lane * 4];

    const int t0 = blockIdx.x * 32 + w * 8;
#pragma unroll
    for (int i = 0; i < 8; i++) {
        const int t = t0 + i;
        const float* xr = x + (size_t)t * DMODEL;
        ushort* xbr = Xb + (size_t)t * DMODEL;
        float acc[4] = {0.f, 0.f, 0.f, 0.f};
#pragma unroll
        for (int p = 0; p < 4; p++) {
            float4 xv = *(const float4*)&xr[p * 256 + lane * 4];
            ushort4 o;
            o.x = f2b(xv.x); o.y = f2b(xv.y); o.z = f2b(xv.z); o.w = f2b(xv.w);
            *(ushort4*)&xbr[p * 256 + lane * 4] = o;
#pragma unroll
            for (int e = 0; e < 4; e++)
                acc[e] += xv.x * wv[p][e].x + xv.y * wv[p][e].y +
                          xv.z * wv[p][e].z + xv.w * wv[p][e].w;
        }
#pragma unroll
        for (int e = 0; e < 4; e++)
#pragma unroll
            for (int s = 1; s < 64; s <<= 1) acc[e] += __shfl_xor(acc[e], s);
        if (lane == 0) {
            int i0 = 0; float v0 = acc[0];
#pragma unroll
            for (int e = 1; e < 4; e++) if (acc[e] > v0) { v0 = acc[e]; i0 = e; }
            int i1 = -1; float v1 = -INFINITY;
#pragma unroll
            for (int e = 0; e < 4; e++) if (e != i0 && acc[e] > v1) { v1 = acc[e]; i1 = e; }
            float e1 = expf(v1 - v0);
            float w0 = 1.0f / (1.0f + e1);
            float w1 = e1 / (1.0f + e1);
            float o[4] = {0.f, 0.f, 0.f, 0.f};
            o[i0] = w0; o[i1] = w1;
            *(float4*)&gdense[t * 4] = make_float4(o[0], o[1], o[2], o[3]);
            top2s[w * 8 + i] = i0 | (i1 << 4);
        }
    }
    __syncthreads();
    if (w == 0) {
        int i0 = -1, i1 = -1;
        if (lane < 32) {
            const int pk = top2s[lane];
            i0 = pk & 15; i1 = pk >> 4;
        }
        const unsigned long long below = (1ull << lane) - 1;
        const int t = blockIdx.x * 32 + lane;
#pragma unroll
        for (int e = 0; e < 4; e++) {
            unsigned long long m0 = __ballot(i0 == e);
            unsigned long long m1 = __ballot(i1 == e);
            const int c0 = __popcll(m0);
            const int c1 = __popcll(m1);
            int base = 0;
            if (lane == 0 && (c0 + c1) > 0) base = atomicAdd(&counts[e], c0 + c1);
            base = __shfl(base, 0);
            if (i0 == e) {
                const int p = base + __popcll(m0 & below);
                lists[e * T_TOK + p] = t;
                inv[2 * t] = (e << 16) | p;
            }
            if (i1 == e) {
                const int p = base + c0 + __popcll(m1 & below);
                lists[e * T_TOK + p] = t;
                inv[2 * t + 1] = (e << 16) | p;
            }
        }
    }
}

// ---------------- fp32 [Kd][Nd] -> bf16 [Nd][Kd] (batched over z) -------------
__global__ void transpose_cvt(const float* __restrict__ in, ushort* __restrict__ out,
                              int Kd, int Nd) {
    __shared__ float tile[32][33];
    const size_t mat = (size_t)Kd * Nd;
    const float* ip = in + (size_t)blockIdx.z * mat;
    ushort* op = out + (size_t)blockIdx.z * mat;
    const int n0 = blockIdx.x * 32, k0 = blockIdx.y * 32;
    const int tx = threadIdx.x, ty = threadIdx.y;  // (32, 8)
#pragma unroll
    for (int j = 0; j < 4; j++)
        tile[ty + j * 8][tx] = ip[(size_t)(k0 + ty + j * 8) * Nd + n0 + tx];
    __syncthreads();
#pragma unroll
    for (int j = 0; j < 4; j++)
        op[(size_t)(n0 + ty + j * 8) * Kd + k0 + tx] = f2b(tile[tx][ty + j * 8]);
}

// ==== 256x256 tile, BK=32, WAVE TILE 128x64, depth-2 counted vmcnt, swizzle ===
// LDS-pipe math (256 B/clk): wave 128x64 reads 12 b128 per 32 MFMA ->
// per 8-wave block-step ~384 read-cy + 128 write-cy vs 310 MFMA-cy/SIMD
// (vs 128^2 structures where LDS >= 2x MFMA -> the R12-R18 ~650 TF plateau).
// 3 LDS buffers (96 KB, 1 block/CU); R13's proven loop: per step
// vmcnt(4) [tile t's 4 loads, issued 2 iters back] -> s_barrier ->
// stage(t+2) -> compute(t). Never drains to 0 mid-loop; depth-2 (2 steps
// ~1024 cy) covers HBM latency with no cross-block TLP needed.
// Swizzle (R17-proven, 0 conflicts): granule g of row r at g ^ ((r>>1)&3);
// pre-swizzled global src (linear glds dest) + swizzled ds_read addr.
template <int PHASE, bool ROUTED>
__launch_bounds__(512, 2)
__global__ void ffn_gemm256(const ushort* __restrict__ Abase,
                            ushort* __restrict__ hOut,
                            ushort* __restrict__ uOut,
                            const ushort* __restrict__ Wbase,
                            const float* __restrict__ biasBase,
                            const float* __restrict__ gdense,
                            const int* __restrict__ lists,
                            const int* __restrict__ counts) {
    constexpr int Nn = (PHASE == 1) ? HFFN : DMODEL;
    constexpr int Kd = (PHASE == 1) ? DMODEL : HFFN;
    constexpr int NCT = Nn / 256;
    constexpr int NSEC = ROUTED ? NEXP : 1;
    constexpr int P = NSEC * NCT;          // 16 / 64 / 16 — all %8==0
    constexpr int PER8 = P / 8;
    constexpr int BK = 32;
    constexpr int nk = Kd / BK;

    __shared__ ushort As[3][256 * BK];     // 16 KB each
    __shared__ ushort Bs[3][256 * BK];

    const int id = blockIdx.x;
    const int rt = id / P;
    const int pos = id % P;
    const int inner = (pos & 7) * PER8 + (pos >> 3);   // XCD-bijective
    const int sec = inner / NCT;
    const int ct = inner % NCT;

    const int cnt = ROUTED ? counts[sec] : T_TOK;
    const int row0 = rt * 256;
    if (row0 >= cnt) return;
    const int col0 = ct * 256;
    int pfx = 0;
    if (ROUTED) for (int i = 0; i < sec; i++) pfx += counts[i];
    const int* list_s = ROUTED ? (lists + sec * T_TOK) : nullptr;
    const ushort* Bt = Wbase + (ROUTED ? (size_t)sec * Kd * Nn : 0);
    const float* bias = biasBase + (ROUTED ? sec * Nn : 0);

    const int tid = threadIdx.x;
    const int lane = tid & 63, wid = tid >> 6;
    const int wr = wid >> 2, wc = wid & 3;   // 2M x 4N waves, wave tile 128x64
    const int lnr = lane & 15, lhi = lane >> 4;

    // ---- staging: 4 glds16/thread (A rows s_r, s_r+128; B same) --------------
    const int s_r = tid >> 2;              // 0..127
    const int sg = tid & 3;
    const int gsw = sg ^ ((s_r >> 1) & 3); // (s_r+128)>>1 keeps &3 -> same gsw

    int a0 = row0 + s_r;        if (a0 >= cnt) a0 = cnt - 1;
    int a1 = row0 + 128 + s_r;  if (a1 >= cnt) a1 = cnt - 1;
    size_t ar0, ar1;
    if (PHASE == 1) {
        ar0 = ROUTED ? (size_t)list_s[a0] : (size_t)a0;
        ar1 = ROUTED ? (size_t)list_s[a1] : (size_t)a1;
    } else {
        ar0 = (size_t)(pfx + a0);
        ar1 = (size_t)(pfx + a1);
    }
    const ushort* Ap0 = Abase + ar0 * Kd + gsw * 8;
    const ushort* Ap1 = Abase + ar1 * Kd + gsw * 8;
    const ushort* Bp0 = Bt + (size_t)(col0 + s_r) * Kd + gsw * 8;
    const ushort* Bp1 = Bt + (size_t)(col0 + 128 + s_r) * Kd + gsw * 8;

    auto stage = [&](int buf, int k0) {
        ushort* da = As[buf] + tid * 8;    // linear: row*32 + sg*8 = tid*8
        ushort* db = Bs[buf] + tid * 8;
        glds16(Ap0 + k0, da);
        glds16(Ap1 + k0, da + 4096);       // rows 128..255
        glds16(Bp0 + k0, db);
        glds16(Bp1 + k0, db + 4096);
    };

    f32x4 acc[8][4] = {};

    auto compute = [&](int buf) {
        short8 a[8], b[4];
        const char* Ab = (const char*)As[buf];
        const char* Bb = (const char*)Bs[buf];
#pragma unroll
        for (int mf = 0; mf < 8; mf++) {
            const int row = wr * 128 + mf * 16 + lnr;
            a[mf] = *(const short8*)(Ab + row * 64 + ((lhi ^ ((row >> 1) & 3)) << 4));
        }
#pragma unroll
        for (int nf = 0; nf < 4; nf++) {
            const int row = wc * 64 + nf * 16 + lnr;
            b[nf] = *(const short8*)(Bb + row * 64 + ((lhi ^ ((row >> 1) & 3)) << 4));
        }
#pragma unroll
        for (int mf = 0; mf < 8; mf++)
#pragma unroll
            for (int nf = 0; nf < 4; nf++)
                acc[mf][nf] = __builtin_amdgcn_mfma_f32_16x16x32_bf16(a[mf], b[nf], acc[mf][nf], 0, 0, 0);
    };

    // prologue: two K-tiles in flight
    stage(0, 0);
    stage(1, BK);
    for (int t = 0; t < nk; ++t) {
        if (t == nk - 1) {
            asm volatile("s_waitcnt vmcnt(0)" ::: "memory");
        } else {
            asm volatile("s_waitcnt vmcnt(4)" ::: "memory");  // tile t landed
        }
        __builtin_amdgcn_s_barrier();      // buf t%3 ready for all; (t-1)%3 free
        if (t + 2 < nk) stage((t + 2) % 3, (t + 2) * BK);
        compute(t % 3);
    }

    // epilogue: C/D layout col = lane&15, row = (lane>>4)*4 + j  [verified R15]
#pragma unroll
    for (int mf = 0; mf < 8; mf++) {
        const int r_base = row0 + wr * 128 + mf * 16 + lhi * 4;
#pragma unroll
        for (int nf = 0; nf < 4; nf++) {
            const int c = col0 + wc * 64 + nf * 16 + lnr;
            const float bb = bias[c];
#pragma unroll
            for (int jj = 0; jj < 4; jj++) {
                const int r = r_base + jj;
                if (r >= cnt) continue;
                float v = acc[mf][nf][jj] + bb;
                if (PHASE == 1) {
                    hOut[(size_t)(pfx + r) * HFFN + c] = f2b(gelu_f(v));
                } else {  // PHASE2 ROUTED
                    const int tok = list_s[r];
                    const float g = gdense[tok * 4 + sec];
                    uOut[(size_t)(pfx + r) * DMODEL + c] = f2b(g * v);
                }
            }
        }
    }
}

// ==== thin 128x128 8-wave kernel (R17 config) — used for shared GEMM2 only ====
template <int PHASE, bool ROUTED>
__launch_bounds__(512, 6)
__global__ void ffn_gemm(const ushort* __restrict__ Abase,
                         ushort* __restrict__ hOut,
                         ushort* __restrict__ uOut,
                         float* __restrict__ yOut,
                         const ushort* __restrict__ Wbase,
                         const float* __restrict__ biasBase,
                         const float* __restrict__ gdense,
                         const int* __restrict__ lists,
                         const int* __restrict__ counts) {
    constexpr int Nn = (PHASE == 1) ? HFFN : DMODEL;
    constexpr int Kd = (PHASE == 1) ? DMODEL : HFFN;
    constexpr int NC = Nn / 128;
    constexpr int NSEC = ROUTED ? NEXP : 1;
    constexpr int P = NSEC * NC;
    constexpr int PER8 = (P >= 8) ? P / 8 : 1;
    constexpr int BK = 32;

    __shared__ ushort As[2][128 * BK];
    __shared__ ushort Bs[2][128 * BK];

    const int id = blockIdx.x;
    const int rt = id / P;
    const int pos = id % P;
    const int inner = (pos & 7) * PER8 + (pos >> 3);
    const int sec = inner / NC;
    const int ct = inner % NC;

    const int cnt = ROUTED ? counts[sec] : T_TOK;
    const int row0 = rt * 128;
    if (row0 >= cnt) return;
    const int col0 = ct * 128;
    int pfx = 0;
    if (ROUTED) for (int i = 0; i < sec; i++) pfx += counts[i];
    const int* list_s = ROUTED ? (lists + sec * T_TOK) : nullptr;
    const ushort* Bt = Wbase + (ROUTED ? (size_t)sec * Kd * Nn : 0);
    const float* bias = biasBase + (ROUTED ? sec * Nn : 0);

    const int tid = threadIdx.x;
    const int lane = tid & 63, wid = tid >> 6;
    const int rowbase = (wid >> 1) * 32;   // 4 M-waves
    const int colbase = (wid & 1) * 64;    // 2 N-waves

    const int s_r = tid >> 2;              // row 0..127
    const int sg = tid & 3;
    const int gsw = sg ^ ((s_r >> 1) & 3);

    int l0 = row0 + s_r; if (l0 >= cnt) l0 = cnt - 1;
    size_t ar0;
    if (PHASE == 1) ar0 = ROUTED ? (size_t)list_s[l0] : (size_t)l0;
    else            ar0 = (size_t)(pfx + l0);
    const ushort* Ap0 = Abase + ar0 * Kd + gsw * 8;
    const ushort* Bp0 = Bt + (size_t)(col0 + s_r) * Kd + gsw * 8;

    auto stage = [&](int buf, int k0) {
        glds16(Ap0 + k0, &As[buf][wid * 512]);
        glds16(Bp0 + k0, &Bs[buf][wid * 512]);
    };

    f32x4 acc[2][4] = {};
    const int lr = lane & 15, lhi = lane >> 4;

    auto compute = [&](int buf) {
        short8 af[2], bf[4];
#pragma unroll
        for (int m = 0; m < 2; m++) {
            const int row = rowbase + m * 16 + lr;
            af[m] = *(const short8*)&As[buf][row * 32 + ((lhi ^ ((row >> 1) & 3)) * 8)];
        }
#pragma unroll
        for (int n = 0; n < 4; n++) {
            const int row = colbase + n * 16 + lr;
            bf[n] = *(const short8*)&Bs[buf][row * 32 + ((lhi ^ ((row >> 1) & 3)) * 8)];
        }
#pragma unroll
        for (int m = 0; m < 2; m++)
#pragma unroll
            for (int n = 0; n < 4; n++)
                acc[m][n] = __builtin_amdgcn_mfma_f32_16x16x32_bf16(af[m], bf[n], acc[m][n], 0, 0, 0);
    };

    stage(0, 0);
    __syncthreads();
    int cur = 0;
    constexpr int nk = Kd / BK;
    for (int t = 0; t < nk - 1; ++t) {
        stage(cur ^ 1, (t + 1) * BK);
        compute(cur);
        __syncthreads();
        cur ^= 1;
    }
    compute(cur);

    const int lq = lane >> 4;
#pragma unroll
    for (int m = 0; m < 2; m++) {
        const int r_base = row0 + rowbase + m * 16 + lq * 4;
#pragma unroll
        for (int n = 0; n < 4; n++) {
            const int c = col0 + colbase + n * 16 + lr;
            const float bb = bias[c];
#pragma unroll
            for (int j = 0; j < 4; j++) {
                const int r = r_base + j;
                if (r >= cnt) continue;
                float v = acc[m][n][j] + bb;
                if (PHASE == 1) {
                    hOut[(size_t)(pfx + r) * HFFN + c] = f2b(gelu_f(v));
                } else if (ROUTED) {
                    const int tok = list_s[r];
                    const float g = gdense[tok * 4 + sec];
                    uOut[(size_t)(pfx + r) * DMODEL + c] = f2b(g * v);
                } else {
                    yOut[(size_t)r * DMODEL + c] = v;
                }
            }
        }
    }
}

// -------- combine: out[t][c] (holds shared fp32) += parts[idx0] + parts[idx1] --
__global__ __launch_bounds__(256) void combine_kernel(
        float* __restrict__ out, const ushort* __restrict__ parts,
        const int* __restrict__ inv, const int* __restrict__ counts) {
    const int t = blockIdx.x;
    const int c = threadIdx.x * 4;
    const int c0 = counts[0], c1 = counts[1], c2 = counts[2];
    const int v0 = inv[2 * t], v1 = inv[2 * t + 1];
    const int e0 = v0 >> 16, e1 = v1 >> 16;
    const int pfx0 = (e0 > 0 ? c0 : 0) + (e0 > 1 ? c1 : 0) + (e0 > 2 ? c2 : 0);
    const int pfx1 = (e1 > 0 ? c0 : 0) + (e1 > 1 ? c1 : 0) + (e1 > 2 ? c2 : 0);
    const size_t r0 = (size_t)(pfx0 + (v0 & 0xffff)) * DMODEL + c;
    const size_t r1 = (size_t)(pfx1 + (v1 & 0xffff)) * DMODEL + c;
    float* op = out + (size_t)t * DMODEL + c;
    float4 o = *(float4*)op;
    ushort4 a = *(const ushort4*)&parts[r0];
    ushort4 b = *(const ushort4*)&parts[r1];
    o.x += b2f(a.x) + b2f(b.x);
    o.y += b2f(a.y) + b2f(b.y);
    o.z += b2f(a.z) + b2f(b.z);
    o.w += b2f(a.w) + b2f(b.w);
    *(float4*)op = o;
}

extern "C" void kernel_launch(void* const* d_in, const int* in_sizes, int n_in,
                              void* d_out, int out_size, void* d_ws, size_t ws_size,
                              hipStream_t stream) {
    const float* x      = (const float*)d_in[0];
    const float* gate_w = (const float*)d_in[1];
    const float* W1     = (const float*)d_in[2];
    const float* b1     = (const float*)d_in[3];
    const float* W2     = (const float*)d_in[4];
    const float* b2     = (const float*)d_in[5];
    const float* sW1    = (const float*)d_in[6];
    const float* sb1    = (const float*)d_in[7];
    const float* sW2    = (const float*)d_in[8];
    const float* sb2    = (const float*)d_in[9];
    float* out = (float*)d_out;

    // ---- lifetime-phased workspace, peak ~192.3 MiB (R10-R18 proven safe) ----
    char* ws = (char*)d_ws;
    ushort* hArea  = (ushort*)(ws);
    ushort* Xb     = (ushort*)(ws + (size_t)128 * 1024 * 1024);
    ushort* W1t    = (ushort*)(ws + (size_t)144 * 1024 * 1024);
    ushort* sW1t   = W1t;                                            // [144,152)
    ushort* sW2t   = (ushort*)(ws + (size_t)152 * 1024 * 1024);
    ushort* W2t    = (ushort*)(ws + (size_t)128 * 1024 * 1024);      // after routedG1
    ushort* parts  = (ushort*)(ws + (size_t)160 * 1024 * 1024);
    float*  gdense = (float*)(ws + (size_t)192 * 1024 * 1024);
    int*    counts = (int*)(ws + (size_t)192 * 1024 * 1024 + 131072);
    int*    lists  = (int*)(ws + (size_t)192 * 1024 * 1024 + 131072 + 256);
    int*    inv    = (int*)(ws + (size_t)192 * 1024 * 1024 + 131072 + 256 + 131072);

    hipMemsetAsync(counts, 0, NEXP * sizeof(int), stream);

    gate_kernel<<<T_TOK / 32, 256, 0, stream>>>(x, gate_w, Xb, gdense, counts, lists, inv);

    // ---- shared expert (h rows [0,8192) of hArea; out gets fp32 shared y) ----
    transpose_cvt<<<dim3(HFFN / 32, DMODEL / 32, 1), dim3(32, 8), 0, stream>>>(sW1, sW1t, DMODEL, HFFN);
    transpose_cvt<<<dim3(DMODEL / 32, HFFN / 32, 1), dim3(32, 8), 0, stream>>>(sW2, sW2t, HFFN, DMODEL);
    ffn_gemm256<1, false><<<32 * 16, 512, 0, stream>>>(Xb, hArea, nullptr, sW1t, sb1,
                                                       nullptr, nullptr, nullptr);
    ffn_gemm<2, false><<<64 * 8, 512, 0, stream>>>(hArea, nullptr, nullptr, out, sW2t, sb2,
                                                   nullptr, nullptr, nullptr);

    // ---- routed experts, batched, 256^2 fat-wave kernel ----
    transpose_cvt<<<dim3(HFFN / 32, DMODEL / 32, NEXP), dim3(32, 8), 0, stream>>>(W1, W1t, DMODEL, HFFN);
    ffn_gemm256<1, true><<<32 * 64, 512, 0, stream>>>(Xb, hArea, nullptr, W1t, b1,
                                                      nullptr, lists, counts);
    transpose_cvt<<<dim3(DMODEL / 32, HFFN / 32, NEXP), dim3(32, 8), 0, stream>>>(W2, W2t, HFFN, DMODEL);
    ffn_gemm256<2, true><<<32 * 16, 512, 0, stream>>>(hArea, nullptr, parts, W2t, b2,
                                                      gdense, lists, counts);

    combine_kernel<<<T_TOK, 256, 0, stream>>>(out, parts, inv, counts);
}

// Round 20
// 713.267 us; speedup vs baseline: 1.2025x; 1.2025x over previous
//
#include <hip/hip_runtime.h>
#include <hip/hip_bf16.h>

typedef __attribute__((ext_vector_type(8))) short short8;
typedef __attribute__((ext_vector_type(4))) float f32x4;

#define T_TOK 8192
#define DMODEL 1024
#define HFFN 4096
#define NEXP 4

__device__ __forceinline__ ushort f2b(float f) {
    __hip_bfloat16 h = __float2bfloat16(f);
    return __builtin_bit_cast(ushort, h);
}
__device__ __forceinline__ float b2f(unsigned u) {  // low 16 bits = bf16
    return __builtin_bit_cast(float, u << 16);
}

__device__ __forceinline__ void glds16(const void* g, void* l) {
    __builtin_amdgcn_global_load_lds(
        (__attribute__((address_space(1))) void*)g,
        (__attribute__((address_space(3))) void*)l, 16, 0, 0);
}

__device__ __forceinline__ float gelu_f(float v) {
    float v2 = v * v;
    float t2 = __builtin_fmaf(0.044715f, v2 * v, v);
    float e = __builtin_amdgcn_exp2f(2.3022082f * t2);   // 1.5957691216*log2(e)
    float rr = __builtin_amdgcn_rcpf(e + 1.0f);
    return v - v * rr;
}

// ---------------- gate + x->bf16 fusion + ballot routing + inverse index -----
__global__ __launch_bounds__(256) void gate_kernel(
        const float* __restrict__ x, const float* __restrict__ gw,
        ushort* __restrict__ Xb, float* __restrict__ gdense,
        int* __restrict__ counts, int* __restrict__ lists,
        int* __restrict__ inv) {
    const int lane = threadIdx.x & 63;
    const int w = threadIdx.x >> 6;
    __shared__ int top2s[32];

    float4 wv[4][4];
#pragma unroll
    for (int p = 0; p < 4; p++)
#pragma unroll
        for (int e = 0; e < 4; e++)
            wv[p][e] = *(const float4*)&gw[e * DMODEL + p * 256 + lane * 4];

    const int t0 = blockIdx.x * 32 + w * 8;
#pragma unroll
    for (int i = 0; i < 8; i++) {
        const int t = t0 + i;
        const float* xr = x + (size_t)t * DMODEL;
        ushort* xbr = Xb + (size_t)t * DMODEL;
        float acc[4] = {0.f, 0.f, 0.f, 0.f};
#pragma unroll
        for (int p = 0; p < 4; p++) {
            float4 xv = *(const float4*)&xr[p * 256 + lane * 4];
            ushort4 o;
            o.x = f2b(xv.x); o.y = f2b(xv.y); o.z = f2b(xv.z); o.w = f2b(xv.w);
            *(ushort4*)&xbr[p * 256 + lane * 4] = o;
#pragma unroll
            for (int e = 0; e < 4; e++)
                acc[e] += xv.x * wv[p][e].x + xv.y * wv[p][e].y +
                          xv.z * wv[p][e].z + xv.w * wv[p][e].w;
        }
#pragma unroll
        for (int e = 0; e < 4; e++)
#pragma unroll
            for (int s = 1; s < 64; s <<= 1) acc[e] += __shfl_xor(acc[e], s);
        if (lane == 0) {
            int i0 = 0; float v0 = acc[0];
#pragma unroll
            for (int e = 1; e < 4; e++) if (acc[e] > v0) { v0 = acc[e]; i0 = e; }
            int i1 = -1; float v1 = -INFINITY;
#pragma unroll
            for (int e = 0; e < 4; e++) if (e != i0 && acc[e] > v1) { v1 = acc[e]; i1 = e; }
            float e1 = expf(v1 - v0);
            float w0 = 1.0f / (1.0f + e1);
            float w1 = e1 / (1.0f + e1);
            float o[4] = {0.f, 0.f, 0.f, 0.f};
            o[i0] = w0; o[i1] = w1;
            *(float4*)&gdense[t * 4] = make_float4(o[0], o[1], o[2], o[3]);
            top2s[w * 8 + i] = i0 | (i1 << 4);
        }
    }
    __syncthreads();
    if (w == 0) {
        int i0 = -1, i1 = -1;
        if (lane < 32) {
            const int pk = top2s[lane];
            i0 = pk & 15; i1 = pk >> 4;
        }
        const unsigned long long below = (1ull << lane) - 1;
        const int t = blockIdx.x * 32 + lane;
#pragma unroll
        for (int e = 0; e < 4; e++) {
            unsigned long long m0 = __ballot(i0 == e);
            unsigned long long m1 = __ballot(i1 == e);
            const int c0 = __popcll(m0);
            const int c1 = __popcll(m1);
            int base = 0;
            if (lane == 0 && (c0 + c1) > 0) base = atomicAdd(&counts[e], c0 + c1);
            base = __shfl(base, 0);
            if (i0 == e) {
                const int p = base + __popcll(m0 & below);
                lists[e * T_TOK + p] = t;
                inv[2 * t] = (e << 16) | p;
            }
            if (i1 == e) {
                const int p = base + c0 + __popcll(m1 & below);
                lists[e * T_TOK + p] = t;
                inv[2 * t + 1] = (e << 16) | p;
            }
        }
    }
}

// ---------------- fp32 [Kd][Nd] -> bf16 [Nd][Kd] (batched over z) -------------
__global__ void transpose_cvt(const float* __restrict__ in, ushort* __restrict__ out,
                              int Kd, int Nd) {
    __shared__ float tile[32][33];
    const size_t mat = (size_t)Kd * Nd;
    const float* ip = in + (size_t)blockIdx.z * mat;
    ushort* op = out + (size_t)blockIdx.z * mat;
    const int n0 = blockIdx.x * 32, k0 = blockIdx.y * 32;
    const int tx = threadIdx.x, ty = threadIdx.y;  // (32, 8)
#pragma unroll
    for (int j = 0; j < 4; j++)
        tile[ty + j * 8][tx] = ip[(size_t)(k0 + ty + j * 8) * Nd + n0 + tx];
    __syncthreads();
#pragma unroll
    for (int j = 0; j < 4; j++)
        op[(size_t)(n0 + ty + j * 8) * Kd + k0 + tx] = f2b(tile[tx][ty + j * 8]);
}

// ==== FFN GEMM, 128x256 block, BK=32, 2-phase, 8 waves of 64x64, swizzled =====
// LDS/FLOP fix over R17: wave tile 64x64 -> (4+4) b128-reads per 16 MFMA
// (0.5/MFMA vs thin 32x64's 0.75). LDS 48 KB (A 8K + B 16K, x2 buf) -> 3
// blocks/CU; regs ~116 unified -> 4 waves/SIMD cap -> 24 waves/CU (= R17's
// proven TLP level that hides the 2-phase barrier drain).
// Swizzle (R17-proven, 0 conflicts): granule g of row r at g ^ ((r>>1)&3);
// pre-swizzled global src (linear glds dest) + swizzled ds_read addr.
// Grid: rt OUTER (128-row tiles), (sec,ct) inner XCD-bijective (R12-proven).
// PHASE1: h[(pfx+r)][c] = gelu(v+b1)  (A gathered if ROUTED)
// PHASE2 ROUTED:  parts[(pfx+r)*D+c] = bf16(g*(v+b2))
// PHASE2 !ROUTED: yOut[r*D+c] = v + sb2
template <int PHASE, bool ROUTED>
__launch_bounds__(512, 4)
__global__ void ffn_gemm(const ushort* __restrict__ Abase,
                         ushort* __restrict__ hOut,
                         ushort* __restrict__ uOut,
                         float* __restrict__ yOut,
                         const ushort* __restrict__ Wbase,
                         const float* __restrict__ biasBase,
                         const float* __restrict__ gdense,
                         const int* __restrict__ lists,
                         const int* __restrict__ counts) {
    constexpr int Nn = (PHASE == 1) ? HFFN : DMODEL;
    constexpr int Kd = (PHASE == 1) ? DMODEL : HFFN;
    constexpr int NC = Nn / 256;           // 256-wide col tiles
    constexpr int NSEC = ROUTED ? NEXP : 1;
    constexpr int P = NSEC * NC;           // 64 / 16 / 16 — all %8==0
    constexpr int PER8 = (P >= 8) ? P / 8 : 1;
    constexpr int BK = 32;

    __shared__ ushort As[2][128 * BK];     // 8 KB each
    __shared__ ushort Bs[2][256 * BK];     // 16 KB each

    const int id = blockIdx.x;
    const int rt = id / P;
    const int pos = id % P;
    const int inner = (pos & 7) * PER8 + (pos >> 3);
    const int sec = inner / NC;
    const int ct = inner % NC;

    const int cnt = ROUTED ? counts[sec] : T_TOK;
    const int row0 = rt * 128;
    if (row0 >= cnt) return;
    const int col0 = ct * 256;
    int pfx = 0;
    if (ROUTED) for (int i = 0; i < sec; i++) pfx += counts[i];
    const int* list_s = ROUTED ? (lists + sec * T_TOK) : nullptr;
    const ushort* Bt = Wbase + (ROUTED ? (size_t)sec * Kd * Nn : 0);
    const float* bias = biasBase + (ROUTED ? sec * Nn : 0);

    const int tid = threadIdx.x;
    const int lane = tid & 63, wid = tid >> 6;
    const int wr = wid >> 2, wc = wid & 3;   // 2M x 4N waves, wave tile 64x64
    const int lnr = lane & 15, lhi = lane >> 4;

    // staging: 1 glds16 A + 2 glds16 B per thread; PRE-SWIZZLED global source.
    const int s_r = tid >> 2;              // row 0..127
    const int sg = tid & 3;
    const int gsw = sg ^ ((s_r >> 1) & 3); // +128 rows keep the same gsw

    int l0 = row0 + s_r; if (l0 >= cnt) l0 = cnt - 1;
    size_t ar0;
    if (PHASE == 1) ar0 = ROUTED ? (size_t)list_s[l0] : (size_t)l0;
    else            ar0 = (size_t)(pfx + l0);
    const ushort* Ap0 = Abase + ar0 * Kd + gsw * 8;
    const ushort* Bp0 = Bt + (size_t)(col0 + s_r) * Kd + gsw * 8;
    const ushort* Bp1 = Bt + (size_t)(col0 + 128 + s_r) * Kd + gsw * 8;

    auto stage = [&](int buf, int k0) {
        glds16(Ap0 + k0, &As[buf][tid * 8]);            // linear: row*32+g*8
        glds16(Bp0 + k0, &Bs[buf][tid * 8]);
        glds16(Bp1 + k0, &Bs[buf][4096 + tid * 8]);     // B rows 128..255
    };

    f32x4 acc[4][4] = {};

    auto compute = [&](int buf) {
        short8 af[4], bf[4];
#pragma unroll
        for (int m = 0; m < 4; m++) {
            const int row = wr * 64 + m * 16 + lnr;
            af[m] = *(const short8*)&As[buf][row * 32 + ((lhi ^ ((row >> 1) & 3)) * 8)];
        }
#pragma unroll
        for (int n = 0; n < 4; n++) {
            const int row = wc * 64 + n * 16 + lnr;
            bf[n] = *(const short8*)&Bs[buf][row * 32 + ((lhi ^ ((row >> 1) & 3)) * 8)];
        }
#pragma unroll
        for (int m = 0; m < 4; m++)
#pragma unroll
            for (int n = 0; n < 4; n++)
                acc[m][n] = __builtin_amdgcn_mfma_f32_16x16x32_bf16(af[m], bf[n], acc[m][n], 0, 0, 0);
    };

    stage(0, 0);
    __syncthreads();
    int cur = 0;
    constexpr int nk = Kd / BK;
    for (int t = 0; t < nk - 1; ++t) {
        stage(cur ^ 1, (t + 1) * BK);
        compute(cur);
        __syncthreads();
        cur ^= 1;
    }
    compute(cur);

    // epilogue: C/D layout col = lane&15, row = (lane>>4)*4 + j  [verified]
    const int lq = lane >> 4;
#pragma unroll
    for (int m = 0; m < 4; m++) {
        const int r_base = row0 + wr * 64 + m * 16 + lq * 4;
#pragma unroll
        for (int n = 0; n < 4; n++) {
            const int c = col0 + wc * 64 + n * 16 + lnr;
            const float bb = bias[c];
#pragma unroll
            for (int j = 0; j < 4; j++) {
                const int r = r_base + j;
                if (r >= cnt) continue;
                float v = acc[m][n][j] + bb;
                if (PHASE == 1) {
                    hOut[(size_t)(pfx + r) * HFFN + c] = f2b(gelu_f(v));
                } else if (ROUTED) {
                    const int tok = list_s[r];
                    const float g = gdense[tok * 4 + sec];
                    uOut[(size_t)(pfx + r) * DMODEL + c] = f2b(g * v);
                } else {
                    yOut[(size_t)r * DMODEL + c] = v;
                }
            }
        }
    }
}

// ==== thin 128x128 8-wave kernel (R17 config) — used for shared GEMM2 only ====
template <int PHASE, bool ROUTED>
__launch_bounds__(512, 6)
__global__ void ffn_gemm_thin(const ushort* __restrict__ Abase,
                              ushort* __restrict__ hOut,
                              ushort* __restrict__ uOut,
                              float* __restrict__ yOut,
                              const ushort* __restrict__ Wbase,
                              const float* __restrict__ biasBase,
                              const float* __restrict__ gdense,
                              const int* __restrict__ lists,
                              const int* __restrict__ counts) {
    constexpr int Nn = (PHASE == 1) ? HFFN : DMODEL;
    constexpr int Kd = (PHASE == 1) ? DMODEL : HFFN;
    constexpr int NC = Nn / 128;
    constexpr int NSEC = ROUTED ? NEXP : 1;
    constexpr int P = NSEC * NC;
    constexpr int PER8 = (P >= 8) ? P / 8 : 1;
    constexpr int BK = 32;

    __shared__ ushort As[2][128 * BK];
    __shared__ ushort Bs[2][128 * BK];

    const int id = blockIdx.x;
    const int rt = id / P;
    const int pos = id % P;
    const int inner = (pos & 7) * PER8 + (pos >> 3);
    const int sec = inner / NC;
    const int ct = inner % NC;

    const int cnt = ROUTED ? counts[sec] : T_TOK;
    const int row0 = rt * 128;
    if (row0 >= cnt) return;
    const int col0 = ct * 128;
    int pfx = 0;
    if (ROUTED) for (int i = 0; i < sec; i++) pfx += counts[i];
    const int* list_s = ROUTED ? (lists + sec * T_TOK) : nullptr;
    const ushort* Bt = Wbase + (ROUTED ? (size_t)sec * Kd * Nn : 0);
    const float* bias = biasBase + (ROUTED ? sec * Nn : 0);

    const int tid = threadIdx.x;
    const int lane = tid & 63, wid = tid >> 6;
    const int rowbase = (wid >> 1) * 32;   // 4 M-waves
    const int colbase = (wid & 1) * 64;    // 2 N-waves

    const int s_r = tid >> 2;              // row 0..127
    const int sg = tid & 3;
    const int gsw = sg ^ ((s_r >> 1) & 3);

    int l0 = row0 + s_r; if (l0 >= cnt) l0 = cnt - 1;
    size_t ar0;
    if (PHASE == 1) ar0 = ROUTED ? (size_t)list_s[l0] : (size_t)l0;
    else            ar0 = (size_t)(pfx + l0);
    const ushort* Ap0 = Abase + ar0 * Kd + gsw * 8;
    const ushort* Bp0 = Bt + (size_t)(col0 + s_r) * Kd + gsw * 8;

    auto stage = [&](int buf, int k0) {
        glds16(Ap0 + k0, &As[buf][wid * 512]);
        glds16(Bp0 + k0, &Bs[buf][wid * 512]);
    };

    f32x4 acc[2][4] = {};
    const int lr = lane & 15, lhi = lane >> 4;

    auto compute = [&](int buf) {
        short8 af[2], bf[4];
#pragma unroll
        for (int m = 0; m < 2; m++) {
            const int row = rowbase + m * 16 + lr;
            af[m] = *(const short8*)&As[buf][row * 32 + ((lhi ^ ((row >> 1) & 3)) * 8)];
        }
#pragma unroll
        for (int n = 0; n < 4; n++) {
            const int row = colbase + n * 16 + lr;
            bf[n] = *(const short8*)&Bs[buf][row * 32 + ((lhi ^ ((row >> 1) & 3)) * 8)];
        }
#pragma unroll
        for (int m = 0; m < 2; m++)
#pragma unroll
            for (int n = 0; n < 4; n++)
                acc[m][n] = __builtin_amdgcn_mfma_f32_16x16x32_bf16(af[m], bf[n], acc[m][n], 0, 0, 0);
    };

    stage(0, 0);
    __syncthreads();
    int cur = 0;
    constexpr int nk = Kd / BK;
    for (int t = 0; t < nk - 1; ++t) {
        stage(cur ^ 1, (t + 1) * BK);
        compute(cur);
        __syncthreads();
        cur ^= 1;
    }
    compute(cur);

    const int lq = lane >> 4;
#pragma unroll
    for (int m = 0; m < 2; m++) {
        const int r_base = row0 + rowbase + m * 16 + lq * 4;
#pragma unroll
        for (int n = 0; n < 4; n++) {
            const int c = col0 + colbase + n * 16 + lr;
            const float bb = bias[c];
#pragma unroll
            for (int j = 0; j < 4; j++) {
                const int r = r_base + j;
                if (r >= cnt) continue;
                float v = acc[m][n][j] + bb;
                if (PHASE == 1) {
                    hOut[(size_t)(pfx + r) * HFFN + c] = f2b(gelu_f(v));
                } else if (ROUTED) {
                    const int tok = list_s[r];
                    const float g = gdense[tok * 4 + sec];
                    uOut[(size_t)(pfx + r) * DMODEL + c] = f2b(g * v);
                } else {
                    yOut[(size_t)r * DMODEL + c] = v;
                }
            }
        }
    }
}

// -------- combine: out[t][c] (holds shared fp32) += parts[idx0] + parts[idx1] --
__global__ __launch_bounds__(256) void combine_kernel(
        float* __restrict__ out, const ushort* __restrict__ parts,
        const int* __restrict__ inv, const int* __restrict__ counts) {
    const int t = blockIdx.x;
    const int c = threadIdx.x * 4;
    const int c0 = counts[0], c1 = counts[1], c2 = counts[2];
    const int v0 = inv[2 * t], v1 = inv[2 * t + 1];
    const int e0 = v0 >> 16, e1 = v1 >> 16;
    const int pfx0 = (e0 > 0 ? c0 : 0) + (e0 > 1 ? c1 : 0) + (e0 > 2 ? c2 : 0);
    const int pfx1 = (e1 > 0 ? c0 : 0) + (e1 > 1 ? c1 : 0) + (e1 > 2 ? c2 : 0);
    const size_t r0 = (size_t)(pfx0 + (v0 & 0xffff)) * DMODEL + c;
    const size_t r1 = (size_t)(pfx1 + (v1 & 0xffff)) * DMODEL + c;
    float* op = out + (size_t)t * DMODEL + c;
    float4 o = *(float4*)op;
    ushort4 a = *(const ushort4*)&parts[r0];
    ushort4 b = *(const ushort4*)&parts[r1];
    o.x += b2f(a.x) + b2f(b.x);
    o.y += b2f(a.y) + b2f(b.y);
    o.z += b2f(a.z) + b2f(b.z);
    o.w += b2f(a.w) + b2f(b.w);
    *(float4*)op = o;
}

extern "C" void kernel_launch(void* const* d_in, const int* in_sizes, int n_in,
                              void* d_out, int out_size, void* d_ws, size_t ws_size,
                              hipStream_t stream) {
    const float* x      = (const float*)d_in[0];
    const float* gate_w = (const float*)d_in[1];
    const float* W1     = (const float*)d_in[2];
    const float* b1     = (const float*)d_in[3];
    const float* W2     = (const float*)d_in[4];
    const float* b2     = (const float*)d_in[5];
    const float* sW1    = (const float*)d_in[6];
    const float* sb1    = (const float*)d_in[7];
    const float* sW2    = (const float*)d_in[8];
    const float* sb2    = (const float*)d_in[9];
    float* out = (float*)d_out;

    // ---- lifetime-phased workspace, peak ~192.3 MiB (R10-R19 proven safe) ----
    char* ws = (char*)d_ws;
    ushort* hArea  = (ushort*)(ws);
    ushort* Xb     = (ushort*)(ws + (size_t)128 * 1024 * 1024);
    ushort* W1t    = (ushort*)(ws + (size_t)144 * 1024 * 1024);
    ushort* sW1t   = W1t;                                            // [144,152)
    ushort* sW2t   = (ushort*)(ws + (size_t)152 * 1024 * 1024);
    ushort* W2t    = (ushort*)(ws + (size_t)128 * 1024 * 1024);      // after routedG1
    ushort* parts  = (ushort*)(ws + (size_t)160 * 1024 * 1024);
    float*  gdense = (float*)(ws + (size_t)192 * 1024 * 1024);
    int*    counts = (int*)(ws + (size_t)192 * 1024 * 1024 + 131072);
    int*    lists  = (int*)(ws + (size_t)192 * 1024 * 1024 + 131072 + 256);
    int*    inv    = (int*)(ws + (size_t)192 * 1024 * 1024 + 131072 + 256 + 131072);

    hipMemsetAsync(counts, 0, NEXP * sizeof(int), stream);

    gate_kernel<<<T_TOK / 32, 256, 0, stream>>>(x, gate_w, Xb, gdense, counts, lists, inv);

    // ---- shared expert (h rows [0,8192) of hArea; out gets fp32 shared y) ----
    transpose_cvt<<<dim3(HFFN / 32, DMODEL / 32, 1), dim3(32, 8), 0, stream>>>(sW1, sW1t, DMODEL, HFFN);
    transpose_cvt<<<dim3(DMODEL / 32, HFFN / 32, 1), dim3(32, 8), 0, stream>>>(sW2, sW2t, HFFN, DMODEL);
    ffn_gemm<1, false><<<64 * 16, 512, 0, stream>>>(Xb, hArea, nullptr, nullptr, sW1t, sb1,
                                                    nullptr, nullptr, nullptr);
    ffn_gemm_thin<2, false><<<64 * 8, 512, 0, stream>>>(hArea, nullptr, nullptr, out, sW2t, sb2,
                                                        nullptr, nullptr, nullptr);

    // ---- routed experts, batched, 128x256 fat-wave kernel ----
    transpose_cvt<<<dim3(HFFN / 32, DMODEL / 32, NEXP), dim3(32, 8), 0, stream>>>(W1, W1t, DMODEL, HFFN);
    ffn_gemm<1, true><<<64 * NEXP * 16, 512, 0, stream>>>(Xb, hArea, nullptr, nullptr, W1t, b1,
                                                          nullptr, lists, counts);
    transpose_cvt<<<dim3(DMODEL / 32, HFFN / 32, NEXP), dim3(32, 8), 0, stream>>>(W2, W2t, HFFN, DMODEL);
    ffn_gemm<2, true><<<64 * NEXP * 4, 512, 0, stream>>>(hArea, nullptr, parts, nullptr, W2t, b2,
                                                         gdense, lists, counts);

    combine_kernel<<<T_TOK, 256, 0, stream>>>(out, parts, inv, counts);
}

// Round 21
// 673.920 us; speedup vs baseline: 1.2727x; 1.0584x over previous
//
#include <hip/hip_runtime.h>
#include <hip/hip_bf16.h>

typedef __attribute__((ext_vector_type(8))) short short8;
typedef __attribute__((ext_vector_type(4))) float f32x4;

#define T_TOK 8192
#define DMODEL 1024
#define HFFN 4096
#define NEXP 4

__device__ __forceinline__ ushort f2b(float f) {
    __hip_bfloat16 h = __float2bfloat16(f);
    return __builtin_bit_cast(ushort, h);
}
__device__ __forceinline__ float b2f(unsigned u) {  // low 16 bits = bf16
    return __builtin_bit_cast(float, u << 16);
}

__device__ __forceinline__ void glds16(const void* g, void* l) {
    __builtin_amdgcn_global_load_lds(
        (__attribute__((address_space(1))) void*)g,
        (__attribute__((address_space(3))) void*)l, 16, 0, 0);
}

__device__ __forceinline__ float gelu_f(float v) {
    float v2 = v * v;
    float t2 = __builtin_fmaf(0.044715f, v2 * v, v);
    float e = __builtin_amdgcn_exp2f(2.3022082f * t2);   // 1.5957691216*log2(e)
    float rr = __builtin_amdgcn_rcpf(e + 1.0f);
    return v - v * rr;
}

// ---------------- gate + x->bf16 fusion + ballot routing + inverse index -----
__global__ __launch_bounds__(256) void gate_kernel(
        const float* __restrict__ x, const float* __restrict__ gw,
        ushort* __restrict__ Xb, float* __restrict__ gdense,
        int* __restrict__ counts, int* __restrict__ lists,
        int* __restrict__ inv) {
    const int lane = threadIdx.x & 63;
    const int w = threadIdx.x >> 6;
    __shared__ int top2s[32];

    float4 wv[4][4];
#pragma unroll
    for (int p = 0; p < 4; p++)
#pragma unroll
        for (int e = 0; e < 4; e++)
            wv[p][e] = *(const float4*)&gw[e * DMODEL + p * 256 + lane * 4];

    const int t0 = blockIdx.x * 32 + w * 8;
#pragma unroll
    for (int i = 0; i < 8; i++) {
        const int t = t0 + i;
        const float* xr = x + (size_t)t * DMODEL;
        ushort* xbr = Xb + (size_t)t * DMODEL;
        float acc[4] = {0.f, 0.f, 0.f, 0.f};
#pragma unroll
        for (int p = 0; p < 4; p++) {
            float4 xv = *(const float4*)&xr[p * 256 + lane * 4];
            ushort4 o;
            o.x = f2b(xv.x); o.y = f2b(xv.y); o.z = f2b(xv.z); o.w = f2b(xv.w);
            *(ushort4*)&xbr[p * 256 + lane * 4] = o;
#pragma unroll
            for (int e = 0; e < 4; e++)
                acc[e] += xv.x * wv[p][e].x + xv.y * wv[p][e].y +
                          xv.z * wv[p][e].z + xv.w * wv[p][e].w;
        }
#pragma unroll
        for (int e = 0; e < 4; e++)
#pragma unroll
            for (int s = 1; s < 64; s <<= 1) acc[e] += __shfl_xor(acc[e], s);
        if (lane == 0) {
            int i0 = 0; float v0 = acc[0];
#pragma unroll
            for (int e = 1; e < 4; e++) if (acc[e] > v0) { v0 = acc[e]; i0 = e; }
            int i1 = -1; float v1 = -INFINITY;
#pragma unroll
            for (int e = 0; e < 4; e++) if (e != i0 && acc[e] > v1) { v1 = acc[e]; i1 = e; }
            float e1 = expf(v1 - v0);
            float w0 = 1.0f / (1.0f + e1);
            float w1 = e1 / (1.0f + e1);
            float o[4] = {0.f, 0.f, 0.f, 0.f};
            o[i0] = w0; o[i1] = w1;
            *(float4*)&gdense[t * 4] = make_float4(o[0], o[1], o[2], o[3]);
            top2s[w * 8 + i] = i0 | (i1 << 4);
        }
    }
    __syncthreads();
    if (w == 0) {
        int i0 = -1, i1 = -1;
        if (lane < 32) {
            const int pk = top2s[lane];
            i0 = pk & 15; i1 = pk >> 4;
        }
        const unsigned long long below = (1ull << lane) - 1;
        const int t = blockIdx.x * 32 + lane;
#pragma unroll
        for (int e = 0; e < 4; e++) {
            unsigned long long m0 = __ballot(i0 == e);
            unsigned long long m1 = __ballot(i1 == e);
            const int c0 = __popcll(m0);
            const int c1 = __popcll(m1);
            int base = 0;
            if (lane == 0 && (c0 + c1) > 0) base = atomicAdd(&counts[e], c0 + c1);
            base = __shfl(base, 0);
            if (i0 == e) {
                const int p = base + __popcll(m0 & below);
                lists[e * T_TOK + p] = t;
                inv[2 * t] = (e << 16) | p;
            }
            if (i1 == e) {
                const int p = base + c0 + __popcll(m1 & below);
                lists[e * T_TOK + p] = t;
                inv[2 * t + 1] = (e << 16) | p;
            }
        }
    }
}

// ---------------- fp32 [Kd][Nd] -> bf16 [Nd][Kd] (batched over z) -------------
__global__ void transpose_cvt(const float* __restrict__ in, ushort* __restrict__ out,
                              int Kd, int Nd) {
    __shared__ float tile[32][33];
    const size_t mat = (size_t)Kd * Nd;
    const float* ip = in + (size_t)blockIdx.z * mat;
    ushort* op = out + (size_t)blockIdx.z * mat;
    const int n0 = blockIdx.x * 32, k0 = blockIdx.y * 32;
    const int tx = threadIdx.x, ty = threadIdx.y;  // (32, 8)
#pragma unroll
    for (int j = 0; j < 4; j++)
        tile[ty + j * 8][tx] = ip[(size_t)(k0 + ty + j * 8) * Nd + n0 + tx];
    __syncthreads();
#pragma unroll
    for (int j = 0; j < 4; j++)
        op[(size_t)(n0 + ty + j * 8) * Kd + k0 + tx] = f2b(tile[tx][ty + j * 8]);
}

// ==== FFN GEMM, 128x128 tile, BK=32, 2-phase, 8 waves, XOR-swizzled LDS =======
// R17 config — best measured (675 us total). MfmaUtil 29% == this wave shape's
// LDS-pipe roofline (6 b128 reads + stage share ~32 CU-cy vs 9.7 MFMA cy/SIMD
// per wave-K-step); 0 bank conflicts; 60% occupancy hides the barrier drain.
// Fatter wave tiles (44-61% caps) all collapsed occupancy (R18/R19/R20).
template <int PHASE, bool ROUTED>
__launch_bounds__(512, 6)
__global__ void ffn_gemm(const ushort* __restrict__ Abase,
                         ushort* __restrict__ hOut,
                         ushort* __restrict__ uOut,
                         float* __restrict__ yOut,
                         const ushort* __restrict__ Wbase,
                         const float* __restrict__ biasBase,
                         const float* __restrict__ gdense,
                         const int* __restrict__ lists,
                         const int* __restrict__ counts) {
    constexpr int Nn = (PHASE == 1) ? HFFN : DMODEL;
    constexpr int Kd = (PHASE == 1) ? DMODEL : HFFN;
    constexpr int NC = Nn / 128;
    constexpr int NSEC = ROUTED ? NEXP : 1;
    constexpr int P = NSEC * NC;
    constexpr int PER8 = (P >= 8) ? P / 8 : 1;
    constexpr int BK = 32;

    __shared__ ushort As[2][128 * BK];
    __shared__ ushort Bs[2][128 * BK];

    const int id = blockIdx.x;
    const int rt = id / P;
    const int pos = id % P;
    const int inner = (pos & 7) * PER8 + (pos >> 3);
    const int sec = inner / NC;
    const int ct = inner % NC;

    const int cnt = ROUTED ? counts[sec] : T_TOK;
    const int row0 = rt * 128;
    if (row0 >= cnt) return;
    const int col0 = ct * 128;
    int pfx = 0;
    if (ROUTED) for (int i = 0; i < sec; i++) pfx += counts[i];
    const int* list_s = ROUTED ? (lists + sec * T_TOK) : nullptr;
    const ushort* Bt = Wbase + (ROUTED ? (size_t)sec * Kd * Nn : 0);
    const float* bias = biasBase + (ROUTED ? sec * Nn : 0);

    const int tid = threadIdx.x;
    const int lane = tid & 63, wid = tid >> 6;
    const int rowbase = (wid >> 1) * 32;   // 4 M-waves
    const int colbase = (wid & 1) * 64;    // 2 N-waves

    // staging: 1 glds16 A + 1 glds16 B per thread; PRE-SWIZZLED global source.
    const int s_r = tid >> 2;              // row 0..127
    const int sg = tid & 3;                // linear dest granule
    const int gsw = sg ^ ((s_r >> 1) & 3); // swizzled source granule

    int l0 = row0 + s_r; if (l0 >= cnt) l0 = cnt - 1;
    size_t ar0;
    if (PHASE == 1) ar0 = ROUTED ? (size_t)list_s[l0] : (size_t)l0;
    else            ar0 = (size_t)(pfx + l0);
    const ushort* Ap0 = Abase + ar0 * Kd + gsw * 8;
    const ushort* Bp0 = Bt + (size_t)(col0 + s_r) * Kd + gsw * 8;

    auto stage = [&](int buf, int k0) {
        glds16(Ap0 + k0, &As[buf][wid * 512]);   // linear dest: tid*16B
        glds16(Bp0 + k0, &Bs[buf][wid * 512]);
    };

    f32x4 acc[2][4] = {};
    const int lr = lane & 15, lhi = lane >> 4;

    auto compute = [&](int buf) {
        short8 af[2], bf[4];
#pragma unroll
        for (int m = 0; m < 2; m++) {
            const int row = rowbase + m * 16 + lr;
            af[m] = *(const short8*)&As[buf][row * 32 + ((lhi ^ ((row >> 1) & 3)) * 8)];
        }
#pragma unroll
        for (int n = 0; n < 4; n++) {
            const int row = colbase + n * 16 + lr;
            bf[n] = *(const short8*)&Bs[buf][row * 32 + ((lhi ^ ((row >> 1) & 3)) * 8)];
        }
#pragma unroll
        for (int m = 0; m < 2; m++)
#pragma unroll
            for (int n = 0; n < 4; n++)
                acc[m][n] = __builtin_amdgcn_mfma_f32_16x16x32_bf16(af[m], bf[n], acc[m][n], 0, 0, 0);
    };

    stage(0, 0);
    __syncthreads();
    int cur = 0;
    constexpr int nk = Kd / BK;
    for (int t = 0; t < nk - 1; ++t) {
        stage(cur ^ 1, (t + 1) * BK);
        compute(cur);
        __syncthreads();
        cur ^= 1;
    }
    compute(cur);

    // epilogue: C/D layout col = lane&15, row = (lane>>4)*4 + j  [verified]
    const int lq = lane >> 4;
#pragma unroll
    for (int m = 0; m < 2; m++) {
        const int r_base = row0 + rowbase + m * 16 + lq * 4;
#pragma unroll
        for (int n = 0; n < 4; n++) {
            const int c = col0 + colbase + n * 16 + lr;
            const float bb = bias[c];
#pragma unroll
            for (int j = 0; j < 4; j++) {
                const int r = r_base + j;
                if (r >= cnt) continue;
                float v = acc[m][n][j] + bb;
                if (PHASE == 1) {
                    hOut[(size_t)(pfx + r) * HFFN + c] = f2b(gelu_f(v));
                } else if (ROUTED) {
                    const int tok = list_s[r];
                    const float g = gdense[tok * 4 + sec];
                    uOut[(size_t)(pfx + r) * DMODEL + c] = f2b(g * v);
                } else {
                    yOut[(size_t)r * DMODEL + c] = v;
                }
            }
        }
    }
}

// -------- combine: out[t][c] (holds shared fp32) += parts[idx0] + parts[idx1] --
__global__ __launch_bounds__(256) void combine_kernel(
        float* __restrict__ out, const ushort* __restrict__ parts,
        const int* __restrict__ inv, const int* __restrict__ counts) {
    const int t = blockIdx.x;
    const int c = threadIdx.x * 4;
    const int c0 = counts[0], c1 = counts[1], c2 = counts[2];
    const int v0 = inv[2 * t], v1 = inv[2 * t + 1];
    const int e0 = v0 >> 16, e1 = v1 >> 16;
    const int pfx0 = (e0 > 0 ? c0 : 0) + (e0 > 1 ? c1 : 0) + (e0 > 2 ? c2 : 0);
    const int pfx1 = (e1 > 0 ? c0 : 0) + (e1 > 1 ? c1 : 0) + (e1 > 2 ? c2 : 0);
    const size_t r0 = (size_t)(pfx0 + (v0 & 0xffff)) * DMODEL + c;
    const size_t r1 = (size_t)(pfx1 + (v1 & 0xffff)) * DMODEL + c;
    float* op = out + (size_t)t * DMODEL + c;
    float4 o = *(float4*)op;
    ushort4 a = *(const ushort4*)&parts[r0];
    ushort4 b = *(const ushort4*)&parts[r1];
    o.x += b2f(a.x) + b2f(b.x);
    o.y += b2f(a.y) + b2f(b.y);
    o.z += b2f(a.z) + b2f(b.z);
    o.w += b2f(a.w) + b2f(b.w);
    *(float4*)op = o;
}

extern "C" void kernel_launch(void* const* d_in, const int* in_sizes, int n_in,
                              void* d_out, int out_size, void* d_ws, size_t ws_size,
                              hipStream_t stream) {
    const float* x      = (const float*)d_in[0];
    const float* gate_w = (const float*)d_in[1];
    const float* W1     = (const float*)d_in[2];
    const float* b1     = (const float*)d_in[3];
    const float* W2     = (const float*)d_in[4];
    const float* b2     = (const float*)d_in[5];
    const float* sW1    = (const float*)d_in[6];
    const float* sb1    = (const float*)d_in[7];
    const float* sW2    = (const float*)d_in[8];
    const float* sb2    = (const float*)d_in[9];
    float* out = (float*)d_out;

    // ---- lifetime-phased workspace, peak ~192.3 MiB (R10-R20 proven safe) ----
    char* ws = (char*)d_ws;
    ushort* hArea  = (ushort*)(ws);
    ushort* Xb     = (ushort*)(ws + (size_t)128 * 1024 * 1024);
    ushort* W1t    = (ushort*)(ws + (size_t)144 * 1024 * 1024);
    ushort* sW1t   = W1t;                                            // [144,152)
    ushort* sW2t   = (ushort*)(ws + (size_t)152 * 1024 * 1024);
    ushort* W2t    = (ushort*)(ws + (size_t)128 * 1024 * 1024);      // after routedG1
    ushort* parts  = (ushort*)(ws + (size_t)160 * 1024 * 1024);
    float*  gdense = (float*)(ws + (size_t)192 * 1024 * 1024);
    int*    counts = (int*)(ws + (size_t)192 * 1024 * 1024 + 131072);
    int*    lists  = (int*)(ws + (size_t)192 * 1024 * 1024 + 131072 + 256);
    int*    inv    = (int*)(ws + (size_t)192 * 1024 * 1024 + 131072 + 256 + 131072);

    hipMemsetAsync(counts, 0, NEXP * sizeof(int), stream);

    gate_kernel<<<T_TOK / 32, 256, 0, stream>>>(x, gate_w, Xb, gdense, counts, lists, inv);

    // ---- shared expert (h rows [0,8192) of hArea; out gets fp32 shared y) ----
    transpose_cvt<<<dim3(HFFN / 32, DMODEL / 32, 1), dim3(32, 8), 0, stream>>>(sW1, sW1t, DMODEL, HFFN);
    transpose_cvt<<<dim3(DMODEL / 32, HFFN / 32, 1), dim3(32, 8), 0, stream>>>(sW2, sW2t, HFFN, DMODEL);
    ffn_gemm<1, false><<<64 * 32, 512, 0, stream>>>(Xb, hArea, nullptr, nullptr, sW1t, sb1,
                                                    nullptr, nullptr, nullptr);
    ffn_gemm<2, false><<<64 * 8, 512, 0, stream>>>(hArea, nullptr, nullptr, out, sW2t, sb2,
                                                   nullptr, nullptr, nullptr);

    // ---- routed experts, batched ----
    transpose_cvt<<<dim3(HFFN / 32, DMODEL / 32, NEXP), dim3(32, 8), 0, stream>>>(W1, W1t, DMODEL, HFFN);
    ffn_gemm<1, true><<<64 * NEXP * 32, 512, 0, stream>>>(Xb, hArea, nullptr, nullptr, W1t, b1,
                                                          nullptr, lists, counts);
    transpose_cvt<<<dim3(DMODEL / 32, HFFN / 32, NEXP), dim3(32, 8), 0, stream>>>(W2, W2t, HFFN, DMODEL);
    ffn_gemm<2, true><<<64 * NEXP * 8, 512, 0, stream>>>(hArea, nullptr, parts, nullptr, W2t, b2,
                                                         gdense, lists, counts);

    combine_kernel<<<T_TOK, 256, 0, stream>>>(out, parts, inv, counts);
}